// Round 4
// baseline (590.166 us; speedup 1.0000x reference)
//
#include <hip/hip_runtime.h>

// ---------------------------------------------------------------------------
// RPN head on gfx950: x --conv3x3(512->256)+relu--> h1 --conv3x3(256->256)+relu
//   --> h2 --1x1 heads (cls 18 / reg 36)--> softmax pairs --> out (B,H,W,9,6)
// R4: async K-loop. global_load_lds(16B) staging, double-buffered LDS,
// prefetch(it+1) issued BEFORE compute(it) so the vmcnt drain at the barrier
// is ~free. XOR swizzle (seg ^= row&7) applied on the global-side lane map
// keeps LDS linear (DMA requirement) AND bank-uniform. 1 block/CU (131.6 KB).
// ---------------------------------------------------------------------------

typedef float f32x4  __attribute__((ext_vector_type(4)));
typedef float f32x16 __attribute__((ext_vector_type(16)));
typedef short bf16x8 __attribute__((ext_vector_type(8)));   // 8 bf16 = 4 VGPRs

union U16x8 { uint4 v; unsigned short s[8]; };

__device__ __forceinline__ unsigned short f2bf(float f) {
  union { float f; unsigned int u; } v; v.f = f;
  unsigned int r = v.u + 0x7FFFu + ((v.u >> 16) & 1u);   // RNE
  return (unsigned short)(r >> 16);
}

// async global->LDS DMA, 16 B per lane. LDS dest must be uniform base + lane*16.
__device__ __forceinline__ void cp16(const unsigned short* g, unsigned short* l) {
  __builtin_amdgcn_global_load_lds(
      (const __attribute__((address_space(1))) unsigned int*)g,
      (__attribute__((address_space(3))) unsigned int*)l, 16, 0, 0);
}

// ---- transpose + fp32->bf16: src[z][K][N] -> dst[z][N][K] ------------------
__global__ __launch_bounds__(256) void transpose_cvt(
    const float* __restrict__ src, unsigned short* __restrict__ dst,
    int K, int N) {
  __shared__ float t[32][33];
  const int tx = threadIdx.x, ty = threadIdx.y;     // 32 x 8
  const int k0 = blockIdx.x * 32, n0 = blockIdx.y * 32;
  const float* s = src + (size_t)blockIdx.z * K * N;
  unsigned short* d = dst + (size_t)blockIdx.z * N * K;
#pragma unroll
  for (int r = 0; r < 32; r += 8) {
    int k = k0 + ty + r, n = n0 + tx;
    t[ty + r][tx] = (k < K && n < N) ? s[(size_t)k * N + n] : 0.f;
  }
  __syncthreads();
#pragma unroll
  for (int r = 0; r < 32; r += 8) {
    int n = n0 + ty + r, k = k0 + tx;
    if (n < N && k < K) d[(size_t)n * K + k] = f2bf(t[tx][ty + r]);
  }
}

// ---- x (f32 NHWC) -> x_pad (bf16, [4][130][130][512], zero halo) -----------
__global__ __launch_bounds__(256) void convert_x(
    const float* __restrict__ x, unsigned short* __restrict__ xp) {
  int idx = blockIdx.x * 256 + threadIdx.x;       // 4*130*130*64 exactly
  int g = idx & 63;                                // 8-channel group
  int cell = idx >> 6;
  int xpix = cell % 130;
  int t = cell / 130;
  int ypix = t % 130;
  int b = t / 130;
  U16x8 u;
  if (xpix == 0 || xpix == 129 || ypix == 0 || ypix == 129) {
    u.v = make_uint4(0u, 0u, 0u, 0u);
  } else {
    const float* sp = x + ((size_t)((b * 128 + ypix - 1) * 128) + (xpix - 1)) * 512 + g * 8;
    float4 a = *(const float4*)sp;
    float4 c = *(const float4*)(sp + 4);
    u.s[0] = f2bf(a.x); u.s[1] = f2bf(a.y); u.s[2] = f2bf(a.z); u.s[3] = f2bf(a.w);
    u.s[4] = f2bf(c.x); u.s[5] = f2bf(c.y); u.s[6] = f2bf(c.z); u.s[7] = f2bf(c.w);
  }
  *(uint4*)(xp + (size_t)cell * 512 + g * 8) = u.v;
}

// ---- zero the halo of h1_pad: border cells only (4 x 516 x 32 groups) ------
__global__ __launch_bounds__(256) void zero_h1_borders(unsigned short* __restrict__ h1p) {
  int idx = blockIdx.x * 256 + threadIdx.x;        // 66048 exactly
  int g = idx & 31;
  int cell = idx >> 5;                             // 0..2063
  int b = cell / 516, c = cell % 516;
  int row, col;
  if (c < 130)      { row = 0;   col = c; }
  else if (c < 260) { row = 129; col = c - 130; }
  else { int e = c - 260; row = 1 + (e >> 1); col = (e & 1) * 129; }
  size_t ci = ((size_t)(b * 130) + row) * 130 + col;
  *(uint4*)(h1p + ci * 256 + g * 8) = make_uint4(0u, 0u, 0u, 0u);
}

// ---- 3x3 conv: async dbuf implicit GEMM, bf16 MFMA 32x32x16, dx-merged -----
// Ap:  [4][130][130][CIN] bf16 (zero halo).  WT: [9][256][CIN] bf16 (B^T).
// MODE 0: out = h1_pad (interior).  MODE 1: flat NHWC.
// BM=128 (one image row), BN=128, BK=64; iter = (dy, ci0); 96 MFMA/wave/iter.
// LDS linear (no pad) + XOR swizzle seg^=(row&7) done via the DMA lane map.
template<int CIN, int MODE>
__global__ __launch_bounds__(256) void conv3x3(
    const unsigned short* __restrict__ Ap,
    const unsigned short* __restrict__ WT,
    const float* __restrict__ bias,
    unsigned short* __restrict__ out) {
  constexpr int NC = CIN / 64;          // ci0 steps
  constexpr int NI = 3 * NC;            // total iterations (dy outer)
  __shared__ __align__(16) unsigned short As[2][130 * 64];      //  2x16,640 B
  __shared__ __align__(16) unsigned short Bs[2][3 * 128 * 64];  //  2x49,152 B
  const int tid  = threadIdx.x;
  const int wave = tid >> 6, lane = tid & 63;
  const int wm = wave >> 1, wn = wave & 1;
  const int l31 = lane & 31, hi = lane >> 5;
  const int q  = lane >> 3;             // row-in-chunk 0..7
  const int sp = lane & 7;              // physical seg (LDS slot)
  const int sl = sp ^ q;                // logical seg to fetch (swizzle)
  const int b = blockIdx.x >> 7, y = blockIdx.x & 127;
  const int nbase = blockIdx.y * 128;

  // issue async staging for iteration `it` into buffer `buf`
  auto stage = [&](int buf, int it) {
    int dy = it / NC, ci0 = (it - dy * NC) * 64;
    const unsigned short* Arow = Ap + ((size_t)(b * 130 + y + dy) * 130) * CIN + ci0;
    const unsigned short* Bt   = WT + ((size_t)(dy * 3) * 256 + nbase) * CIN + ci0;
    // A: 130 rows x 128 B -> 16 full wave-chunks + 2-row tail
#pragma unroll
    for (int c = wave; c < 16; c += 4) {
      int r = c * 8 + q;                                  // r&7 == q
      cp16(Arow + (size_t)r * CIN + sl * 8, &As[buf][c * 512 + lane * 8]);
    }
    if (wave == 0 && lane < 16) {                         // rows 128,129 (q=0,1)
      int r = 128 + q;
      cp16(Arow + (size_t)r * CIN + sl * 8, &As[buf][16 * 512 + lane * 8]);
    }
    // B: 3 taps x 128 co x 128 B -> 48 wave-chunks
#pragma unroll
    for (int c = wave; c < 48; c += 4) {
      int gi = c * 8 + q;                                 // 0..383, gi&7 == q
      int dx = gi >> 7, rr = gi & 127;
      cp16(Bt + ((size_t)dx * 256 + rr) * CIN + sl * 8, &Bs[buf][c * 512 + lane * 8]);
    }
  };

  f32x16 acc[2][2] = {};

  stage(0, 0);
  __syncthreads();                       // vmcnt(0) drain: buf0 ready
  int cur = 0;
  for (int it = 0; it < NI; ++it) {
    if (it + 1 < NI) stage(cur ^ 1, it + 1);   // async prefetch, no wait
#pragma unroll
    for (int dx = 0; dx < 3; ++dx) {
#pragma unroll
      for (int ks = 0; ks < 4; ++ks) {         // K=16 sub-steps of BK=64
        bf16x8 af[2], bfr[2];
#pragma unroll
        for (int i = 0; i < 2; ++i) {
          int row = wm * 64 + i * 32 + l31 + dx;
          int sgp = (ks * 2 + hi) ^ (row & 7);
          af[i] = *(const bf16x8*)&As[cur][row * 64 + sgp * 8];
        }
#pragma unroll
        for (int j = 0; j < 2; ++j) {
          int rw = wn * 64 + j * 32 + l31;
          int sgp = (ks * 2 + hi) ^ (rw & 7);
          bfr[j] = *(const bf16x8*)&Bs[cur][(dx * 128 + rw) * 64 + sgp * 8];
        }
#pragma unroll
        for (int i = 0; i < 2; ++i)
#pragma unroll
          for (int j = 0; j < 2; ++j)
            acc[i][j] = __builtin_amdgcn_mfma_f32_32x32x16_bf16(af[i], bfr[j], acc[i][j], 0, 0, 0);
      }
    }
    __syncthreads();                     // drains prefetch (issued ~1550 cyc ago)
    cur ^= 1;
  }

  // epilogue: 32x32 C/D layout: col = lane&31, row = (reg&3)+8*(reg>>2)+4*hi
#pragma unroll
  for (int i = 0; i < 2; ++i) {
#pragma unroll
    for (int j = 0; j < 2; ++j) {
      int n = nbase + wn * 64 + j * 32 + l31;
      float bb = bias[n];
#pragma unroll
      for (int reg = 0; reg < 16; ++reg) {
        int m = wm * 64 + i * 32 + (reg & 3) + 8 * (reg >> 2) + 4 * hi;
        float v = fmaxf(acc[i][j][reg] + bb, 0.f);
        size_t off;
        if (MODE == 0)
          off = ((size_t)(b * 130 + y + 1) * 130 + (m + 1)) * 256 + n;
        else
          off = ((size_t)((b * 128 + y) * 128 + m)) * 256 + n;
        out[off] = f2bf(v);
      }
    }
  }
}

// ---- heads: h2[65536][256] x WhT[54(pad 64)][256] + bias, softmax pairs ----
__global__ __launch_bounds__(256) void heads_kernel(
    const unsigned short* __restrict__ h2,
    const unsigned short* __restrict__ WhT,
    const float* __restrict__ br, const float* __restrict__ bc,
    float* __restrict__ out) {
  __shared__ __align__(16) unsigned short As[64][264];
  const int tid = threadIdx.x;
  const int wave = tid >> 6, lane = tid & 63;
  const int quad = lane >> 4, l16 = lane & 15;
  const int pix0 = blockIdx.x * 64;
#pragma unroll
  for (int r = 0; r < 8; ++r) {
    int s = r * 256 + tid;
    int row = s >> 5, seg = s & 31;                  // 64 rows x 32 x 16B
    *(uint4*)&As[row][seg * 8] =
        *(const uint4*)(h2 + (size_t)(pix0 + row) * 256 + seg * 8);
  }
  __syncthreads();
  f32x4 acc[4] = {};
#pragma unroll
  for (int ks = 0; ks < 8; ++ks) {
    bf16x8 af = *(const bf16x8*)&As[wave * 16 + l16][ks * 32 + quad * 8];
#pragma unroll
    for (int j = 0; j < 4; ++j) {
      bf16x8 bfr = *(const bf16x8*)(WhT + (size_t)(j * 16 + l16) * 256 + ks * 32 + quad * 8);
      acc[j] = __builtin_amdgcn_mfma_f32_16x16x32_bf16(af, bfr, acc[j], 0, 0, 0);
    }
  }
#pragma unroll
  for (int j = 0; j < 4; ++j) {
    int n = j * 16 + l16;                            // head channel (cls 0-17, reg 18-53)
    float bias = 0.f;
    if (n < 18) bias = bc[n];
    else if (n < 54) bias = br[n - 18];
#pragma unroll
    for (int r = 0; r < 4; ++r) {
      int p = pix0 + wave * 16 + quad * 4 + r;       // pixel
      float v = acc[j][r] + bias;
      float partner = __shfl_xor(v, 1);              // cls pair (even,odd lanes)
      if (n < 18) {
        float mx = fmaxf(v, partner);
        float e0 = __expf(v - mx), e1 = __expf(partner - mx);
        int a = n >> 1, sl2 = n & 1;
        out[(size_t)p * 54 + a * 6 + sl2] = e0 / (e0 + e1);
      } else if (n < 54) {
        int rr = n - 18, a = rr >> 2, sl2 = (rr & 3) + 2;
        out[(size_t)p * 54 + a * 6 + sl2] = v;
      }
    }
  }
}

// ---------------------------------------------------------------------------
extern "C" void kernel_launch(void* const* d_in, const int* in_sizes, int n_in,
                              void* d_out, int out_size, void* d_ws, size_t ws_size,
                              hipStream_t stream) {
  const float* x  = (const float*)d_in[0];
  const float* W1 = (const float*)d_in[1];
  const float* b1 = (const float*)d_in[2];
  const float* W2 = (const float*)d_in[3];
  const float* b2 = (const float*)d_in[4];
  const float* Wr = (const float*)d_in[5];
  const float* br = (const float*)d_in[6];
  const float* Wc = (const float*)d_in[7];
  const float* bc = (const float*)d_in[8];
  float* out = (float*)d_out;

  // workspace carve-up (bytes)
  constexpr size_t XPAD_B  = 4ull * 130 * 130 * 512 * 2;   //  69,222,400
  constexpr size_t H1PAD_B = 4ull * 130 * 130 * 256 * 2;   //  34,611,200
  constexpr size_t H2_B    = 4ull * 128 * 128 * 256 * 2;   //  33,554,432
  constexpr size_t W1T_B   = 9ull * 256 * 512 * 2;         //   2,359,296
  constexpr size_t W2T_B   = 9ull * 256 * 256 * 2;         //   1,179,648
  char* ws = (char*)d_ws;
  unsigned short* x_pad  = (unsigned short*)(ws);
  unsigned short* h1_pad = (unsigned short*)(ws + XPAD_B);
  unsigned short* h2     = (unsigned short*)(ws + XPAD_B + H1PAD_B);
  unsigned short* W1T    = (unsigned short*)(ws + XPAD_B + H1PAD_B + H2_B);
  unsigned short* W2T    = (unsigned short*)(ws + XPAD_B + H1PAD_B + H2_B + W1T_B);
  unsigned short* WhT    = (unsigned short*)(ws + XPAD_B + H1PAD_B + H2_B + W1T_B + W2T_B);

  // zero the padded head-weight block (rows 54..63 are read by MFMA)
  hipMemsetAsync(WhT, 0, 64ull * 256 * 2, stream);
  // weight repacks (B^T, bf16)
  transpose_cvt<<<dim3(16, 8, 9), dim3(32, 8), 0, stream>>>(W1, W1T, 512, 256);
  transpose_cvt<<<dim3(8, 8, 9),  dim3(32, 8), 0, stream>>>(W2, W2T, 256, 256);
  transpose_cvt<<<dim3(8, 1, 1),  dim3(32, 8), 0, stream>>>(Wc, WhT, 256, 18);
  transpose_cvt<<<dim3(8, 2, 1),  dim3(32, 8), 0, stream>>>(Wr, WhT + 18 * 256, 256, 36);
  // input pad+convert, h1 halo zero (borders only)
  convert_x<<<16900, 256, 0, stream>>>(x, x_pad);
  zero_h1_borders<<<258, 256, 0, stream>>>(h1_pad);
  // conv1: 512ci -> h1_pad ; conv2: 256ci -> h2 flat
  conv3x3<512, 0><<<dim3(512, 2), 256, 0, stream>>>(x_pad, W1T, b1, h1_pad);
  conv3x3<256, 1><<<dim3(512, 2), 256, 0, stream>>>(h1_pad, W2T, b2, h2);
  // 1x1 heads + softmax + interleave
  heads_kernel<<<1024, 256, 0, stream>>>(h2, WhT, br, bc, out);
}